// Round 14
// baseline (49.007 us; speedup 1.0000x reference)
//
#include <hip/hip_runtime.h>
#include <stdint.h>

#define NBATCH 256
#define NQ 900
#define NC 91
#define NQC (NQ * NC)      // 81900
#define KSEL 100
#define IOU_THRF 0.7f
#define CONF_THRF 0.3f
#define TH_LOGIT 2.2f      // static filter; batch 100th logit ~3.03; verified in-kernel
#define DELTA 4096u        // key-ulp tie margin (~1e-3 logit; prob-rounding ties need ~1.3e-6)

// ---- kernel A: streaming filter, deterministic per-slice output ----
#define SLC 8              // slices per batch -> grid 2048 = 8 blocks/CU exactly
#define SF4FULL 2560       // float4 per slice 0..6; slice 7 has 2555 (7*2560+2555 = 20475)
#define SF4LAST 2555
#define ANT 256
#define SCAP 256           // per-slice cap (expected ~142, 9.6-sigma margin)
#define CAPB (SLC * SCAP)  // 2048 max gathered per batch

// ---- kernel B: select + NMS ----
#define BNT 512
#define HBINS 64           // bin = (fkey>>20) - 0xC00
#define SRTCAP 512

// monotone key: ascending uint order == ascending float order
__device__ __forceinline__ uint32_t fkey(float x) {
  uint32_t b = __float_as_uint(x);
  return b ^ ((uint32_t)((int32_t)b >> 31) | 0x80000000u);
}
__device__ __forceinline__ float unfkey(uint32_t k) {
  uint32_t b = (k & 0x80000000u) ? (k ^ 0x80000000u) : ~k;
  return __uint_as_float(b);
}
__device__ __forceinline__ float sigmoidf_ref(float x) {
  return 1.0f / (1.0f + expf(-x));
}

// ======================= kernel A =======================
// Keep (fkey<<32|idx) where logit >= TH_LOGIT. Two batches of 5 named-register
// float4 loads issued up-front (5-deep MLP, no arrays -> no scratch); per-lane
// sparse LDS atomic compaction (R13-proven); private region out.
__global__ __launch_bounds__(ANT, 8) void kfilter(const float* __restrict__ logits,
                                                  uint32_t* __restrict__ cnts,
                                                  unsigned long long* __restrict__ cand) {
  __shared__ unsigned long long lbuf[SCAP];
  __shared__ uint32_t lcnt;

  const int blk = blockIdx.x;            // b*SLC + s
  const int b = blk / SLC;
  const int s = blk - b * SLC;
  const int tid = threadIdx.x;
  const int sf4 = (s == SLC - 1) ? SF4LAST : SF4FULL;
  const float4* lg4 = (const float4*)(logits + (size_t)b * NQC) + (size_t)s * SF4FULL;

  if (tid == 0) lcnt = 0;
  __syncthreads();

#define PROC4(v, ii)                                                           \
  {                                                                            \
    const uint32_t ibase = (uint32_t)((s * SF4FULL + (ii)) * 4);               \
    if ((v).x >= TH_LOGIT) {                                                   \
      uint32_t p = atomicAdd(&lcnt, 1u);                                       \
      if (p < SCAP) lbuf[p] = (((unsigned long long)fkey((v).x)) << 32) | (ibase + 0); \
    }                                                                          \
    if ((v).y >= TH_LOGIT) {                                                   \
      uint32_t p = atomicAdd(&lcnt, 1u);                                       \
      if (p < SCAP) lbuf[p] = (((unsigned long long)fkey((v).y)) << 32) | (ibase + 1); \
    }                                                                          \
    if ((v).z >= TH_LOGIT) {                                                   \
      uint32_t p = atomicAdd(&lcnt, 1u);                                       \
      if (p < SCAP) lbuf[p] = (((unsigned long long)fkey((v).z)) << 32) | (ibase + 2); \
    }                                                                          \
    if ((v).w >= TH_LOGIT) {                                                   \
      uint32_t p = atomicAdd(&lcnt, 1u);                                       \
      if (p < SCAP) lbuf[p] = (((unsigned long long)fkey((v).w)) << 32) | (ibase + 3); \
    }                                                                          \
  }

  // batch 1: 5 loads in flight (j = 0..4), always in-bounds for every slice
  {
    const float4 v0 = lg4[tid];
    const float4 v1 = lg4[tid + ANT];
    const float4 v2 = lg4[tid + 2 * ANT];
    const float4 v3 = lg4[tid + 3 * ANT];
    const float4 v4 = lg4[tid + 4 * ANT];
    PROC4(v0, tid)
    PROC4(v1, tid + ANT)
    PROC4(v2, tid + 2 * ANT)
    PROC4(v3, tid + 3 * ANT)
    PROC4(v4, tid + 4 * ANT)
  }
  // batch 2: j = 5..9; only j=9 can run past the last slice's tail
  {
    const float4 z4 = make_float4(0.f, 0.f, 0.f, 0.f);   // 0 < TH -> auto-fail
    const float4 v5 = lg4[tid + 5 * ANT];
    const float4 v6 = lg4[tid + 6 * ANT];
    const float4 v7 = lg4[tid + 7 * ANT];
    const float4 v8 = lg4[tid + 8 * ANT];
    const bool t9 = (tid + 9 * ANT) < sf4;
    const float4 v9 = t9 ? lg4[tid + 9 * ANT] : z4;
    PROC4(v5, tid + 5 * ANT)
    PROC4(v6, tid + 6 * ANT)
    PROC4(v7, tid + 7 * ANT)
    PROC4(v8, tid + 8 * ANT)
    PROC4(v9, tid + 9 * ANT)
  }
#undef PROC4

  __syncthreads();
  const uint32_t m = lcnt;               // uniform; > SCAP signals fallback to B
  if (tid == 0) cnts[blk] = m;
  const uint32_t mw = m < SCAP ? m : SCAP;
  for (uint32_t i = tid; i < mw; i += ANT)
    cand[(size_t)blk * SCAP + i] = lbuf[i];
}

// ======================= kernel B =======================
union BSMem {
  struct {
    unsigned long long keys[CAPB];                // 16 KB  (fkey<<32 | idx)
    unsigned long long srt[SRTCAP];               // 4 KB survivor keys ((~pbits)<<32 | idx)
  } p;
  struct {
    float iou[KSEL * KSEL];                       // 40 KB
    float box[KSEL][4];
    int keep[KSEL];
  } nms;
};

__global__ __launch_bounds__(BNT) void merge_nms(const uint32_t* __restrict__ cnts,
                                                 const unsigned long long* __restrict__ cand,
                                                 const float* __restrict__ logits,
                                                 const float* __restrict__ pboxes,
                                                 const float* __restrict__ tsizes,
                                                 float* __restrict__ out,
                                                 int force_fallback) {
  __shared__ BSMem sm;
  __shared__ unsigned long long rankbuf[KSEL];    // survives nms-union overwrite
  __shared__ uint32_t scnt[SLC], soff[SLC];
  __shared__ uint32_t s_hist[HBINS];
  __shared__ uint32_t s_n, s_bad, s_cut, s_m;
  __shared__ unsigned long long red[BNT / 64];
  __shared__ unsigned long long s_last;

  const int b = blockIdx.x;
  const int tid = threadIdx.x;
  const float* lg = logits + (size_t)b * NQC;

  bool good = !force_fallback;
  if (good) {
    if (tid < SLC) scnt[tid] = cnts[b * SLC + tid];
    __syncthreads();
    if (tid == 0) {
      uint32_t off = 0, bad = 0;
      for (int i = 0; i < SLC; i++) {
        soff[i] = off;
        if (scnt[i] > SCAP) bad = 1;
        off += scnt[i];
      }
      s_n = off;
      s_bad = bad | (off < KSEL ? 1u : 0u);
    }
    __syncthreads();
    good = (s_bad == 0);
  }
  const uint32_t n = good ? s_n : 0;     // <= CAPB structurally

  if (good) {
    // gather slice regions into contiguous LDS list (wave w takes slice w)
    const int wid = tid >> 6, lane = tid & 63;
    for (int sl = wid; sl < SLC; sl += BNT / 64) {
      const uint32_t c = scnt[sl], o = soff[sl];
      for (uint32_t j = lane; j < c; j += 64)
        sm.p.keys[o + j] = cand[((size_t)b * SLC + sl) * SCAP + j];
    }
    if (tid < HBINS) s_hist[tid] = 0;
    if (tid == 0) s_m = 0;
    __syncthreads();

    // 64-bin hist on high key bits (all fkeys >= fkey(2.2) = 0xC00CCCCD)
    for (uint32_t i = tid; i < n; i += BNT) {
      uint32_t k = (uint32_t)(sm.p.keys[i] >> 32);
      uint32_t bin = (k >> 20) - 0xC00u;
      if (bin > HBINS - 1) bin = HBINS - 1;
      atomicAdd(&s_hist[bin], 1u);
    }
    __syncthreads();

    // wave-0 shfl suffix scan over 64 bins -> cut bin holding the batch 100th
    if (tid < 64) {
      uint32_t h = s_hist[tid];
      uint32_t suf = h;
      #pragma unroll
      for (int off = 1; off < 64; off <<= 1) {
        uint32_t t = __shfl_down(suf, off);
        if (tid + off < 64) suf += t;
      }
      bool pred = (suf >= KSEL) && (suf - h < KSEL);   // exactly one lane
      unsigned long long mask = __ballot(pred);
      int cutlane = __ffsll((long long)mask) - 1;      // -1 if none (defensive)
      if (tid == 0) s_cut = (uint32_t)cutlane;
    }
    __syncthreads();
    const uint32_t cut = s_cut;
    if (cut >= HBINS - 1) good = false;                // clamped/invalid bin
    const uint32_t thresh = ((cut + 0xC00u) << 20) - DELTA;

    if (good) {
      // compact survivors; sigmoid only here; srt = (~pbits)<<32 | idx
      for (uint32_t i = tid; i < n; i += BNT) {
        unsigned long long key = sm.p.keys[i];
        uint32_t k = (uint32_t)(key >> 32);
        if (k >= thresh) {
          uint32_t pb = __float_as_uint(sigmoidf_ref(unfkey(k)));
          uint32_t pos = atomicAdd(&s_m, 1u);
          if (pos < SRTCAP)
            sm.p.srt[pos] = (((unsigned long long)(~pb)) << 32) |
                            (key & 0xFFFFFFFFULL);
        }
      }
      __syncthreads();
      const uint32_t m = s_m;
      if (m > SRTCAP) good = false;
      if (good) {
        // barrier-free rank selection: keys unique (idx embedded); ascending
        // rank r < KSEL == position in (prob desc, idx asc) order
        for (uint32_t q = tid; q < m; q += BNT) {
          unsigned long long mykey = sm.p.srt[q];
          uint32_t r = 0;
          for (uint32_t j = 0; j < m; j++)
            r += (sm.p.srt[j] < mykey) ? 1u : 0u;
          if (r < KSEL) rankbuf[r] = mykey;
        }
        __syncthreads();
      }
    }
  }

  if (!good) {
    // exact fallback (never taken on bench data): 100 rounds of block-wide
    // "next element in (prob desc, idx asc) order" over all 81900 logits.
    unsigned long long last = ~0ULL;
    for (int r = 0; r < KSEL; r++) {
      unsigned long long best = 0ULL;
      for (int i = tid; i < NQC; i += BNT) {
        uint32_t pb = __float_as_uint(sigmoidf_ref(lg[i]));
        unsigned long long cmp = (((unsigned long long)pb) << 32) |
                                 (unsigned long long)(~(uint32_t)i);
        if (cmp < last && cmp > best) best = cmp;
      }
      #pragma unroll
      for (int o = 32; o >= 1; o >>= 1) {
        unsigned long long other = __shfl_down(best, o);
        if (other > best) best = other;
      }
      if ((tid & 63) == 0) red[tid >> 6] = best;
      __syncthreads();
      if (tid == 0) {
        unsigned long long mx = red[0];
        for (int w = 1; w < BNT / 64; w++) if (red[w] > mx) mx = red[w];
        s_last = mx;
        uint32_t pb = (uint32_t)(mx >> 32);
        uint32_t id = ~(uint32_t)mx;
        rankbuf[r] = (((unsigned long long)(~pb)) << 32) | (unsigned long long)id;
      }
      __syncthreads();
      last = s_last;
    }
  }

  float score = 0.0f;
  int idx = 0;
  if (tid < KSEL) {
    unsigned long long key = rankbuf[tid];
    score = __uint_as_float(~(uint32_t)(key >> 32));
    idx = (int)(uint32_t)(key & 0xFFFFFFFFu);
  }
  __syncthreads();   // rankbuf reads done before nms union reuse

  const float img_h = tsizes[b * 2 + 0];
  const float img_w = tsizes[b * 2 + 1];
  float* out_scores = out;
  float* out_labels = out + (size_t)NBATCH * KSEL;
  float* out_boxes  = out + (size_t)2 * NBATCH * KSEL;
  float* out_keep   = out + (size_t)2 * NBATCH * KSEL + (size_t)NBATCH * KSEL * 4;

  if (tid < KSEL) {
    int q = idx / NC;
    int lab = idx - q * NC;
    const float* pb = pboxes + ((size_t)b * NQ + q) * 4;
    float cx = pb[0], cy = pb[1], w = pb[2], h = pb[3];
    float hw = __fmul_rn(0.5f, w), hh = __fmul_rn(0.5f, h);
    float x0 = __fmul_rn(__fsub_rn(cx, hw), img_w);
    float y0 = __fmul_rn(__fsub_rn(cy, hh), img_h);
    float x1 = __fmul_rn(__fadd_rn(cx, hw), img_w);
    float y1 = __fmul_rn(__fadd_rn(cy, hh), img_h);
    out_scores[(size_t)b * KSEL + tid] = score;
    out_labels[(size_t)b * KSEL + tid] = (float)lab;
    float* ob = out_boxes + ((size_t)b * KSEL + tid) * 4;
    ob[0] = x0; ob[1] = y0; ob[2] = x1; ob[3] = y1;
    sm.nms.box[tid][0] = x0; sm.nms.box[tid][1] = y0;
    sm.nms.box[tid][2] = x1; sm.nms.box[tid][3] = y1;
  }
  __syncthreads();

  for (int e = tid; e < KSEL * KSEL; e += BNT) {
    int i = e / KSEL;
    int j = e - i * KSEL;
    float ax0 = sm.nms.box[i][0], ay0 = sm.nms.box[i][1];
    float ax1 = sm.nms.box[i][2], ay1 = sm.nms.box[i][3];
    float bx0 = sm.nms.box[j][0], by0 = sm.nms.box[j][1];
    float bx1 = sm.nms.box[j][2], by1 = sm.nms.box[j][3];
    float areaA = __fmul_rn(__fsub_rn(ax1, ax0), __fsub_rn(ay1, ay0));
    float areaB = __fmul_rn(__fsub_rn(bx1, bx0), __fsub_rn(by1, by0));
    float ltx = fmaxf(ax0, bx0), lty = fmaxf(ay0, by0);
    float rbx = fminf(ax1, bx1), rby = fminf(ay1, by1);
    float wx = fmaxf(__fsub_rn(rbx, ltx), 0.0f);
    float wy = fmaxf(__fsub_rn(rby, lty), 0.0f);
    float inter = __fmul_rn(wx, wy);
    float uni = __fsub_rn(__fadd_rn(areaA, areaB), inter);
    sm.nms.iou[e] = __fdiv_rn(inter, fmaxf(uni, 1e-9f));
  }
  __syncthreads();

  // sequential NMS inside wave 0 (shfl, no block barriers)
  if (tid < 64) {
    int keepA = 1;
    int keepB = 1;
    for (int i = 0; i < KSEL; i++) {
      int owner = i & 63;
      int ki = (i < 64) ? __shfl(keepA, owner) : __shfl(keepB, owner);
      if (ki) {
        if (tid > i && sm.nms.iou[i * KSEL + tid] > IOU_THRF) keepA = 0;
        int j = tid + 64;
        if (j < KSEL && j > i && sm.nms.iou[i * KSEL + j] > IOU_THRF) keepB = 0;
      }
    }
    sm.nms.keep[tid] = keepA;
    if (tid + 64 < KSEL) sm.nms.keep[tid + 64] = keepB;
  }
  __syncthreads();

  if (tid < KSEL) {
    float kp = (score > CONF_THRF && sm.nms.keep[tid]) ? 1.0f : 0.0f;
    out_keep[(size_t)b * KSEL + tid] = kp;
  }
}

extern "C" void kernel_launch(void* const* d_in, const int* in_sizes, int n_in,
                              void* d_out, int out_size, void* d_ws, size_t ws_size,
                              hipStream_t stream) {
  const float* logits = (const float*)d_in[0];   // (256, 900, 91) f32
  const float* pboxes = (const float*)d_in[1];   // (256, 900, 4)  f32
  const float* tsizes = (const float*)d_in[2];   // (256, 2)       f32
  (void)in_sizes; (void)n_in; (void)out_size;

  const size_t cnt_bytes = ((size_t)NBATCH * SLC * sizeof(uint32_t) + 255) & ~(size_t)255; // 8.2 KB
  const size_t need = cnt_bytes +
                      (size_t)NBATCH * SLC * SCAP * sizeof(unsigned long long);            // ~4.2 MB
  if (ws_size >= need) {
    uint32_t* cnts = (uint32_t*)d_ws;
    unsigned long long* cand = (unsigned long long*)((char*)d_ws + cnt_bytes);
    kfilter<<<NBATCH * SLC, ANT, 0, stream>>>(logits, cnts, cand);
    merge_nms<<<NBATCH, BNT, 0, stream>>>(cnts, cand, logits, pboxes, tsizes,
                                          (float*)d_out, 0);
  } else {
    // no workspace: exact (slow) fallback path, still correct
    merge_nms<<<NBATCH, BNT, 0, stream>>>(nullptr, nullptr, logits, pboxes, tsizes,
                                          (float*)d_out, 1);
  }
}

// Round 15
// 45.504 us; speedup vs baseline: 1.0770x; 1.0770x over previous
//
#include <hip/hip_runtime.h>
#include <stdint.h>

#define NBATCH 256
#define NQ 900
#define NC 91
#define NQC (NQ * NC)      // 81900
#define NV4 (NQC / 4)      // 20475 float4 per batch, exact
#define KSEL 100
#define IOU_THRF 0.7f
#define CONF_THRF 0.3f
#define TH_LOGIT 2.2f      // static filter; batch 100th logit ~3.03; verified in-kernel
#define DELTA 4096u        // key-ulp tie margin (~1e-3 logit; prob-rounding ties need ~1.3e-6)

#define NT 1024            // one block per batch, 16 waves
#define CAPB 2048          // candidate cap (expected ~1139, 27-sigma margin)
#define HBINS 64           // bin = (fkey>>20) - 0xC00
#define SRTCAP 512

// monotone key: ascending uint order == ascending float order
__device__ __forceinline__ uint32_t fkey(float x) {
  uint32_t b = __float_as_uint(x);
  return b ^ ((uint32_t)((int32_t)b >> 31) | 0x80000000u);
}
__device__ __forceinline__ float unfkey(uint32_t k) {
  uint32_t b = (k & 0x80000000u) ? (k ^ 0x80000000u) : ~k;
  return __uint_as_float(b);
}
__device__ __forceinline__ float sigmoidf_ref(float x) {
  return 1.0f / (1.0f + expf(-x));
}

// ======================= monolithic kernel =======================
// One block per batch. Phase 1: stream 81900 logits, keep (fkey<<32|idx)
// where logit >= TH_LOGIT directly in LDS (no workspace, no 2nd kernel).
// Phase 2: R13-proven select (hist64 -> cut -> DELTA compact -> sigmoid ->
// rank) + IoU/NMS epilogue. All guards -> exact in-block fallback.
union SMem {
  struct {
    unsigned long long keys[CAPB];                // 16 KB  (fkey<<32 | idx)
    unsigned long long srt[SRTCAP];               // 4 KB survivor keys ((~pbits)<<32 | idx)
  } p;
  struct {
    float iou[KSEL * KSEL];                       // 40 KB
    float box[KSEL][4];
    int keep[KSEL];
  } nms;
};

__global__ __launch_bounds__(NT) void postproc(const float* __restrict__ logits,
                                               const float* __restrict__ pboxes,
                                               const float* __restrict__ tsizes,
                                               float* __restrict__ out) {
  __shared__ SMem sm;
  __shared__ unsigned long long rankbuf[KSEL];    // survives nms-union overwrite
  __shared__ uint32_t s_hist[HBINS];
  __shared__ uint32_t s_lcnt, s_cut, s_m;
  __shared__ unsigned long long red[NT / 64];
  __shared__ unsigned long long s_last;

  const int b = blockIdx.x;
  const int tid = threadIdx.x;
  const float* lg = logits + (size_t)b * NQC;
  const float4* lg4 = (const float4*)lg;

  if (tid == 0) s_lcnt = 0;
  __syncthreads();

  // ---------------- phase 1: stream + filter into LDS ----------------
  for (int i = tid; i < NV4; i += NT) {
    float4 v = lg4[i];
    const uint32_t ibase = (uint32_t)(i * 4);
    if (v.x >= TH_LOGIT) {
      uint32_t p = atomicAdd(&s_lcnt, 1u);
      if (p < CAPB) sm.p.keys[p] = (((unsigned long long)fkey(v.x)) << 32) | (ibase + 0);
    }
    if (v.y >= TH_LOGIT) {
      uint32_t p = atomicAdd(&s_lcnt, 1u);
      if (p < CAPB) sm.p.keys[p] = (((unsigned long long)fkey(v.y)) << 32) | (ibase + 1);
    }
    if (v.z >= TH_LOGIT) {
      uint32_t p = atomicAdd(&s_lcnt, 1u);
      if (p < CAPB) sm.p.keys[p] = (((unsigned long long)fkey(v.z)) << 32) | (ibase + 2);
    }
    if (v.w >= TH_LOGIT) {
      uint32_t p = atomicAdd(&s_lcnt, 1u);
      if (p < CAPB) sm.p.keys[p] = (((unsigned long long)fkey(v.w)) << 32) | (ibase + 3);
    }
  }
  __syncthreads();
  const uint32_t n = s_lcnt;
  bool good = (n >= KSEL && n <= CAPB);

  // ---------------- phase 2: select top-100 ----------------
  if (good) {
    if (tid < HBINS) s_hist[tid] = 0;
    if (tid == 0) s_m = 0;
    __syncthreads();

    // 64-bin hist on high key bits (all fkeys >= fkey(2.2) = 0xC00CCCCD)
    for (uint32_t i = tid; i < n; i += NT) {
      uint32_t k = (uint32_t)(sm.p.keys[i] >> 32);
      uint32_t bin = (k >> 20) - 0xC00u;
      if (bin > HBINS - 1) bin = HBINS - 1;
      atomicAdd(&s_hist[bin], 1u);
    }
    __syncthreads();

    // wave-0 shfl suffix scan over 64 bins -> cut bin holding the batch 100th
    if (tid < 64) {
      uint32_t h = s_hist[tid];
      uint32_t suf = h;
      #pragma unroll
      for (int off = 1; off < 64; off <<= 1) {
        uint32_t t = __shfl_down(suf, off);
        if (tid + off < 64) suf += t;
      }
      bool pred = (suf >= KSEL) && (suf - h < KSEL);   // exactly one lane
      unsigned long long mask = __ballot(pred);
      int cutlane = __ffsll((long long)mask) - 1;      // -1 if none (defensive)
      if (tid == 0) s_cut = (uint32_t)cutlane;
    }
    __syncthreads();
    const uint32_t cut = s_cut;
    if (cut >= HBINS - 1) good = false;                // clamped/invalid bin
    const uint32_t thresh = ((cut + 0xC00u) << 20) - DELTA;

    if (good) {
      // compact survivors; sigmoid only here; srt = (~pbits)<<32 | idx
      for (uint32_t i = tid; i < n; i += NT) {
        unsigned long long key = sm.p.keys[i];
        uint32_t k = (uint32_t)(key >> 32);
        if (k >= thresh) {
          uint32_t pb = __float_as_uint(sigmoidf_ref(unfkey(k)));
          uint32_t pos = atomicAdd(&s_m, 1u);
          if (pos < SRTCAP)
            sm.p.srt[pos] = (((unsigned long long)(~pb)) << 32) |
                            (key & 0xFFFFFFFFULL);
        }
      }
      __syncthreads();
      const uint32_t m = s_m;
      if (m > SRTCAP) good = false;
      if (good) {
        // barrier-free rank selection: keys unique (idx embedded); ascending
        // rank r < KSEL == position in (prob desc, idx asc) order
        for (uint32_t q = tid; q < m; q += NT) {
          unsigned long long mykey = sm.p.srt[q];
          uint32_t r = 0;
          for (uint32_t j = 0; j < m; j++)
            r += (sm.p.srt[j] < mykey) ? 1u : 0u;
          if (r < KSEL) rankbuf[r] = mykey;
        }
        __syncthreads();
      }
    }
  }

  if (!good) {
    // exact fallback (never taken on bench data): 100 rounds of block-wide
    // "next element in (prob desc, idx asc) order" over all 81900 logits.
    unsigned long long last = ~0ULL;
    for (int r = 0; r < KSEL; r++) {
      unsigned long long best = 0ULL;
      for (int i = tid; i < NQC; i += NT) {
        uint32_t pb = __float_as_uint(sigmoidf_ref(lg[i]));
        unsigned long long cmp = (((unsigned long long)pb) << 32) |
                                 (unsigned long long)(~(uint32_t)i);
        if (cmp < last && cmp > best) best = cmp;
      }
      #pragma unroll
      for (int o = 32; o >= 1; o >>= 1) {
        unsigned long long other = __shfl_down(best, o);
        if (other > best) best = other;
      }
      if ((tid & 63) == 0) red[tid >> 6] = best;
      __syncthreads();
      if (tid == 0) {
        unsigned long long mx = red[0];
        for (int w = 1; w < NT / 64; w++) if (red[w] > mx) mx = red[w];
        s_last = mx;
        uint32_t pb = (uint32_t)(mx >> 32);
        uint32_t id = ~(uint32_t)mx;
        rankbuf[r] = (((unsigned long long)(~pb)) << 32) | (unsigned long long)id;
      }
      __syncthreads();
      last = s_last;
    }
  }

  // ---------------- epilogue ----------------
  float score = 0.0f;
  int idx = 0;
  if (tid < KSEL) {
    unsigned long long key = rankbuf[tid];
    score = __uint_as_float(~(uint32_t)(key >> 32));
    idx = (int)(uint32_t)(key & 0xFFFFFFFFu);
  }
  __syncthreads();   // rankbuf reads done before nms union reuse

  const float img_h = tsizes[b * 2 + 0];
  const float img_w = tsizes[b * 2 + 1];
  float* out_scores = out;
  float* out_labels = out + (size_t)NBATCH * KSEL;
  float* out_boxes  = out + (size_t)2 * NBATCH * KSEL;
  float* out_keep   = out + (size_t)2 * NBATCH * KSEL + (size_t)NBATCH * KSEL * 4;

  if (tid < KSEL) {
    int q = idx / NC;
    int lab = idx - q * NC;
    const float* pb = pboxes + ((size_t)b * NQ + q) * 4;
    float cx = pb[0], cy = pb[1], w = pb[2], h = pb[3];
    float hw = __fmul_rn(0.5f, w), hh = __fmul_rn(0.5f, h);
    float x0 = __fmul_rn(__fsub_rn(cx, hw), img_w);
    float y0 = __fmul_rn(__fsub_rn(cy, hh), img_h);
    float x1 = __fmul_rn(__fadd_rn(cx, hw), img_w);
    float y1 = __fmul_rn(__fadd_rn(cy, hh), img_h);
    out_scores[(size_t)b * KSEL + tid] = score;
    out_labels[(size_t)b * KSEL + tid] = (float)lab;
    float* ob = out_boxes + ((size_t)b * KSEL + tid) * 4;
    ob[0] = x0; ob[1] = y0; ob[2] = x1; ob[3] = y1;
    sm.nms.box[tid][0] = x0; sm.nms.box[tid][1] = y0;
    sm.nms.box[tid][2] = x1; sm.nms.box[tid][3] = y1;
  }
  __syncthreads();

  for (int e = tid; e < KSEL * KSEL; e += NT) {
    int i = e / KSEL;
    int j = e - i * KSEL;
    float ax0 = sm.nms.box[i][0], ay0 = sm.nms.box[i][1];
    float ax1 = sm.nms.box[i][2], ay1 = sm.nms.box[i][3];
    float bx0 = sm.nms.box[j][0], by0 = sm.nms.box[j][1];
    float bx1 = sm.nms.box[j][2], by1 = sm.nms.box[j][3];
    float areaA = __fmul_rn(__fsub_rn(ax1, ax0), __fsub_rn(ay1, ay0));
    float areaB = __fmul_rn(__fsub_rn(bx1, bx0), __fsub_rn(by1, by0));
    float ltx = fmaxf(ax0, bx0), lty = fmaxf(ay0, by0);
    float rbx = fminf(ax1, bx1), rby = fminf(ay1, by1);
    float wx = fmaxf(__fsub_rn(rbx, ltx), 0.0f);
    float wy = fmaxf(__fsub_rn(rby, lty), 0.0f);
    float inter = __fmul_rn(wx, wy);
    float uni = __fsub_rn(__fadd_rn(areaA, areaB), inter);
    sm.nms.iou[e] = __fdiv_rn(inter, fmaxf(uni, 1e-9f));
  }
  __syncthreads();

  // sequential NMS inside wave 0 (shfl, no block barriers)
  if (tid < 64) {
    int keepA = 1;
    int keepB = 1;
    for (int i = 0; i < KSEL; i++) {
      int owner = i & 63;
      int ki = (i < 64) ? __shfl(keepA, owner) : __shfl(keepB, owner);
      if (ki) {
        if (tid > i && sm.nms.iou[i * KSEL + tid] > IOU_THRF) keepA = 0;
        int j = tid + 64;
        if (j < KSEL && j > i && sm.nms.iou[i * KSEL + j] > IOU_THRF) keepB = 0;
      }
    }
    sm.nms.keep[tid] = keepA;
    if (tid + 64 < KSEL) sm.nms.keep[tid + 64] = keepB;
  }
  __syncthreads();

  if (tid < KSEL) {
    float kp = (score > CONF_THRF && sm.nms.keep[tid]) ? 1.0f : 0.0f;
    out_keep[(size_t)b * KSEL + tid] = kp;
  }
}

extern "C" void kernel_launch(void* const* d_in, const int* in_sizes, int n_in,
                              void* d_out, int out_size, void* d_ws, size_t ws_size,
                              hipStream_t stream) {
  const float* logits = (const float*)d_in[0];   // (256, 900, 91) f32
  const float* pboxes = (const float*)d_in[1];   // (256, 900, 4)  f32
  const float* tsizes = (const float*)d_in[2];   // (256, 2)       f32
  (void)in_sizes; (void)n_in; (void)out_size; (void)d_ws; (void)ws_size;
  postproc<<<NBATCH, NT, 0, stream>>>(logits, pboxes, tsizes, (float*)d_out);
}

// Round 16
// 44.009 us; speedup vs baseline: 1.1136x; 1.0340x over previous
//
#include <hip/hip_runtime.h>
#include <stdint.h>

#define NBATCH 256
#define NQ 900
#define NC 91
#define NQC (NQ * NC)      // 81900
#define NV4 (NQC / 4)      // 20475 float4 per batch, exact
#define KSEL 100
#define IOU_THRF 0.7f
#define CONF_THRF 0.3f
#define TH_LOGIT 2.2f      // static filter; batch 100th logit ~3.03; verified in-kernel
#define DELTA 4096u        // key-ulp tie margin (~1e-3 logit; prob-rounding ties need ~1.3e-6)

#define NT 1024            // one block per batch, 16 waves
#define CAPB 2048          // candidate cap (expected ~1139, 27-sigma margin)
#define HBINS 64           // bin = (fkey>>20) - 0xC00
#define SRTCAP 512

// monotone key: ascending uint order == ascending float order
__device__ __forceinline__ uint32_t fkey(float x) {
  uint32_t b = __float_as_uint(x);
  return b ^ ((uint32_t)((int32_t)b >> 31) | 0x80000000u);
}
__device__ __forceinline__ float unfkey(uint32_t k) {
  uint32_t b = (k & 0x80000000u) ? (k ^ 0x80000000u) : ~k;
  return __uint_as_float(b);
}
__device__ __forceinline__ float sigmoidf_ref(float x) {
  return 1.0f / (1.0f + expf(-x));
}

// ======================= monolithic kernel =======================
// One block per batch. Phase 1: stream 81900 logits with 4-deep named-reg
// MLP, keep (fkey<<32|idx) where logit >= TH_LOGIT directly in LDS.
// Phase 2: R13-proven select (hist64 -> cut -> DELTA compact -> sigmoid ->
// rank) + IoU/NMS epilogue. All guards -> exact in-block fallback.
union SMem {
  struct {
    unsigned long long keys[CAPB];                // 16 KB  (fkey<<32 | idx)
    unsigned long long srt[SRTCAP];               // 4 KB survivor keys ((~pbits)<<32 | idx)
  } p;
  struct {
    float iou[KSEL * KSEL];                       // 40 KB
    float box[KSEL][4];
    int keep[KSEL];
  } nms;
};

__global__ __launch_bounds__(NT) void postproc(const float* __restrict__ logits,
                                               const float* __restrict__ pboxes,
                                               const float* __restrict__ tsizes,
                                               float* __restrict__ out) {
  __shared__ SMem sm;
  __shared__ unsigned long long rankbuf[KSEL];    // survives nms-union overwrite
  __shared__ uint32_t s_hist[HBINS];
  __shared__ uint32_t s_lcnt, s_cut, s_m;
  __shared__ unsigned long long red[NT / 64];
  __shared__ unsigned long long s_last;

  const int b = blockIdx.x;
  const int tid = threadIdx.x;
  const float* lg = logits + (size_t)b * NQC;
  const float4* lg4 = (const float4*)lg;

  if (tid == 0) s_lcnt = 0;
  __syncthreads();

  // ---------------- phase 1: stream + filter into LDS (4-deep MLP) ----------------
#define PROC4(v, ii)                                                           \
  {                                                                            \
    const uint32_t ibase = (uint32_t)((ii) * 4);                               \
    if ((v).x >= TH_LOGIT) {                                                   \
      uint32_t p = atomicAdd(&s_lcnt, 1u);                                     \
      if (p < CAPB) sm.p.keys[p] = (((unsigned long long)fkey((v).x)) << 32) | (ibase + 0); \
    }                                                                          \
    if ((v).y >= TH_LOGIT) {                                                   \
      uint32_t p = atomicAdd(&s_lcnt, 1u);                                     \
      if (p < CAPB) sm.p.keys[p] = (((unsigned long long)fkey((v).y)) << 32) | (ibase + 1); \
    }                                                                          \
    if ((v).z >= TH_LOGIT) {                                                   \
      uint32_t p = atomicAdd(&s_lcnt, 1u);                                     \
      if (p < CAPB) sm.p.keys[p] = (((unsigned long long)fkey((v).z)) << 32) | (ibase + 2); \
    }                                                                          \
    if ((v).w >= TH_LOGIT) {                                                   \
      uint32_t p = atomicAdd(&s_lcnt, 1u);                                     \
      if (p < CAPB) sm.p.keys[p] = (((unsigned long long)fkey((v).w)) << 32) | (ibase + 3); \
    }                                                                          \
  }

  {
    const float4 z4 = make_float4(0.f, 0.f, 0.f, 0.f);   // 0 < TH -> auto-fail
    for (int i = tid; i < NV4; i += 4 * NT) {
      const bool g1 = (i + NT) < NV4;
      const bool g2 = (i + 2 * NT) < NV4;
      const bool g3 = (i + 3 * NT) < NV4;
      const float4 a0 = lg4[i];
      const float4 a1 = g1 ? lg4[i + NT] : z4;
      const float4 a2 = g2 ? lg4[i + 2 * NT] : z4;
      const float4 a3 = g3 ? lg4[i + 3 * NT] : z4;
      PROC4(a0, i)
      PROC4(a1, i + NT)
      PROC4(a2, i + 2 * NT)
      PROC4(a3, i + 3 * NT)
    }
  }
#undef PROC4

  __syncthreads();
  const uint32_t n = s_lcnt;
  bool good = (n >= KSEL && n <= CAPB);

  // ---------------- phase 2: select top-100 ----------------
  if (good) {
    if (tid < HBINS) s_hist[tid] = 0;
    if (tid == 0) s_m = 0;
    __syncthreads();

    // 64-bin hist on high key bits (all fkeys >= fkey(2.2) = 0xC00CCCCD)
    for (uint32_t i = tid; i < n; i += NT) {
      uint32_t k = (uint32_t)(sm.p.keys[i] >> 32);
      uint32_t bin = (k >> 20) - 0xC00u;
      if (bin > HBINS - 1) bin = HBINS - 1;
      atomicAdd(&s_hist[bin], 1u);
    }
    __syncthreads();

    // wave-0 shfl suffix scan over 64 bins -> cut bin holding the batch 100th
    if (tid < 64) {
      uint32_t h = s_hist[tid];
      uint32_t suf = h;
      #pragma unroll
      for (int off = 1; off < 64; off <<= 1) {
        uint32_t t = __shfl_down(suf, off);
        if (tid + off < 64) suf += t;
      }
      bool pred = (suf >= KSEL) && (suf - h < KSEL);   // exactly one lane
      unsigned long long mask = __ballot(pred);
      int cutlane = __ffsll((long long)mask) - 1;      // -1 if none (defensive)
      if (tid == 0) s_cut = (uint32_t)cutlane;
    }
    __syncthreads();
    const uint32_t cut = s_cut;
    if (cut >= HBINS - 1) good = false;                // clamped/invalid bin
    const uint32_t thresh = ((cut + 0xC00u) << 20) - DELTA;

    if (good) {
      // compact survivors; sigmoid only here; srt = (~pbits)<<32 | idx
      for (uint32_t i = tid; i < n; i += NT) {
        unsigned long long key = sm.p.keys[i];
        uint32_t k = (uint32_t)(key >> 32);
        if (k >= thresh) {
          uint32_t pb = __float_as_uint(sigmoidf_ref(unfkey(k)));
          uint32_t pos = atomicAdd(&s_m, 1u);
          if (pos < SRTCAP)
            sm.p.srt[pos] = (((unsigned long long)(~pb)) << 32) |
                            (key & 0xFFFFFFFFULL);
        }
      }
      __syncthreads();
      const uint32_t m = s_m;
      if (m > SRTCAP) good = false;
      if (good) {
        // barrier-free rank selection: keys unique (idx embedded); ascending
        // rank r < KSEL == position in (prob desc, idx asc) order
        for (uint32_t q = tid; q < m; q += NT) {
          unsigned long long mykey = sm.p.srt[q];
          uint32_t r = 0;
          for (uint32_t j = 0; j < m; j++)
            r += (sm.p.srt[j] < mykey) ? 1u : 0u;
          if (r < KSEL) rankbuf[r] = mykey;
        }
        __syncthreads();
      }
    }
  }

  if (!good) {
    // exact fallback (never taken on bench data): 100 rounds of block-wide
    // "next element in (prob desc, idx asc) order" over all 81900 logits.
    unsigned long long last = ~0ULL;
    for (int r = 0; r < KSEL; r++) {
      unsigned long long best = 0ULL;
      for (int i = tid; i < NQC; i += NT) {
        uint32_t pb = __float_as_uint(sigmoidf_ref(lg[i]));
        unsigned long long cmp = (((unsigned long long)pb) << 32) |
                                 (unsigned long long)(~(uint32_t)i);
        if (cmp < last && cmp > best) best = cmp;
      }
      #pragma unroll
      for (int o = 32; o >= 1; o >>= 1) {
        unsigned long long other = __shfl_down(best, o);
        if (other > best) best = other;
      }
      if ((tid & 63) == 0) red[tid >> 6] = best;
      __syncthreads();
      if (tid == 0) {
        unsigned long long mx = red[0];
        for (int w = 1; w < NT / 64; w++) if (red[w] > mx) mx = red[w];
        s_last = mx;
        uint32_t pb = (uint32_t)(mx >> 32);
        uint32_t id = ~(uint32_t)mx;
        rankbuf[r] = (((unsigned long long)(~pb)) << 32) | (unsigned long long)id;
      }
      __syncthreads();
      last = s_last;
    }
  }

  // ---------------- epilogue ----------------
  float score = 0.0f;
  int idx = 0;
  if (tid < KSEL) {
    unsigned long long key = rankbuf[tid];
    score = __uint_as_float(~(uint32_t)(key >> 32));
    idx = (int)(uint32_t)(key & 0xFFFFFFFFu);
  }
  __syncthreads();   // rankbuf reads done before nms union reuse

  const float img_h = tsizes[b * 2 + 0];
  const float img_w = tsizes[b * 2 + 1];
  float* out_scores = out;
  float* out_labels = out + (size_t)NBATCH * KSEL;
  float* out_boxes  = out + (size_t)2 * NBATCH * KSEL;
  float* out_keep   = out + (size_t)2 * NBATCH * KSEL + (size_t)NBATCH * KSEL * 4;

  if (tid < KSEL) {
    int q = idx / NC;
    int lab = idx - q * NC;
    const float* pb = pboxes + ((size_t)b * NQ + q) * 4;
    float cx = pb[0], cy = pb[1], w = pb[2], h = pb[3];
    float hw = __fmul_rn(0.5f, w), hh = __fmul_rn(0.5f, h);
    float x0 = __fmul_rn(__fsub_rn(cx, hw), img_w);
    float y0 = __fmul_rn(__fsub_rn(cy, hh), img_h);
    float x1 = __fmul_rn(__fadd_rn(cx, hw), img_w);
    float y1 = __fmul_rn(__fadd_rn(cy, hh), img_h);
    out_scores[(size_t)b * KSEL + tid] = score;
    out_labels[(size_t)b * KSEL + tid] = (float)lab;
    float* ob = out_boxes + ((size_t)b * KSEL + tid) * 4;
    ob[0] = x0; ob[1] = y0; ob[2] = x1; ob[3] = y1;
    sm.nms.box[tid][0] = x0; sm.nms.box[tid][1] = y0;
    sm.nms.box[tid][2] = x1; sm.nms.box[tid][3] = y1;
  }
  __syncthreads();

  for (int e = tid; e < KSEL * KSEL; e += NT) {
    int i = e / KSEL;
    int j = e - i * KSEL;
    float ax0 = sm.nms.box[i][0], ay0 = sm.nms.box[i][1];
    float ax1 = sm.nms.box[i][2], ay1 = sm.nms.box[i][3];
    float bx0 = sm.nms.box[j][0], by0 = sm.nms.box[j][1];
    float bx1 = sm.nms.box[j][2], by1 = sm.nms.box[j][3];
    float areaA = __fmul_rn(__fsub_rn(ax1, ax0), __fsub_rn(ay1, ay0));
    float areaB = __fmul_rn(__fsub_rn(bx1, bx0), __fsub_rn(by1, by0));
    float ltx = fmaxf(ax0, bx0), lty = fmaxf(ay0, by0);
    float rbx = fminf(ax1, bx1), rby = fminf(ay1, by1);
    float wx = fmaxf(__fsub_rn(rbx, ltx), 0.0f);
    float wy = fmaxf(__fsub_rn(rby, lty), 0.0f);
    float inter = __fmul_rn(wx, wy);
    float uni = __fsub_rn(__fadd_rn(areaA, areaB), inter);
    sm.nms.iou[e] = __fdiv_rn(inter, fmaxf(uni, 1e-9f));
  }
  __syncthreads();

  // sequential NMS inside wave 0 (shfl, no block barriers)
  if (tid < 64) {
    int keepA = 1;
    int keepB = 1;
    for (int i = 0; i < KSEL; i++) {
      int owner = i & 63;
      int ki = (i < 64) ? __shfl(keepA, owner) : __shfl(keepB, owner);
      if (ki) {
        if (tid > i && sm.nms.iou[i * KSEL + tid] > IOU_THRF) keepA = 0;
        int j = tid + 64;
        if (j < KSEL && j > i && sm.nms.iou[i * KSEL + j] > IOU_THRF) keepB = 0;
      }
    }
    sm.nms.keep[tid] = keepA;
    if (tid + 64 < KSEL) sm.nms.keep[tid + 64] = keepB;
  }
  __syncthreads();

  if (tid < KSEL) {
    float kp = (score > CONF_THRF && sm.nms.keep[tid]) ? 1.0f : 0.0f;
    out_keep[(size_t)b * KSEL + tid] = kp;
  }
}

extern "C" void kernel_launch(void* const* d_in, const int* in_sizes, int n_in,
                              void* d_out, int out_size, void* d_ws, size_t ws_size,
                              hipStream_t stream) {
  const float* logits = (const float*)d_in[0];   // (256, 900, 91) f32
  const float* pboxes = (const float*)d_in[1];   // (256, 900, 4)  f32
  const float* tsizes = (const float*)d_in[2];   // (256, 2)       f32
  (void)in_sizes; (void)n_in; (void)out_size; (void)d_ws; (void)ws_size;
  postproc<<<NBATCH, NT, 0, stream>>>(logits, pboxes, tsizes, (float*)d_out);
}